// Round 1
// baseline (509.552 us; speedup 1.0000x reference)
//
#include <hip/hip_runtime.h>
#include <cfloat>
#include <math.h>

#define D_FEAT 64

// ---------------------------------------------------------------------------
// init: out[n][0:64] = inputs[n], out[n][64:128] = -inf sentinel
// one thread = 4 floats of each half (float4)
// ---------------------------------------------------------------------------
__global__ void gcn_init_kernel(const float* __restrict__ inp,
                                float* __restrict__ out, int n_nodes) {
    int idx = blockIdx.x * blockDim.x + threadIdx.x;   // over n_nodes * 16
    int total = n_nodes * 16;
    if (idx >= total) return;
    int n = idx >> 4;
    int q = idx & 15;
    const float4* inp4 = reinterpret_cast<const float4*>(inp);
    float4* out4 = reinterpret_cast<float4*>(out);
    // first half: copy inputs
    out4[(size_t)n * 32 + q] = inp4[(size_t)n * 16 + q];
    // second half: -inf sentinel
    float4 s;
    s.x = -INFINITY; s.y = -INFINITY; s.z = -INFINITY; s.w = -INFINITY;
    out4[(size_t)n * 32 + 16 + q] = s;
}

// ---------------------------------------------------------------------------
// float atomic max via int punning:
//  - non-negative values: signed-int max == float max
//  - negative values: unsigned-int min == float max
// Every op is monotone non-decreasing in float order, so any interleaving
// converges to the true max. Works with -inf (0xFF800000) sentinel.
// ---------------------------------------------------------------------------
__device__ __forceinline__ void atomic_max_float(float* addr, float val) {
    if (__float_as_int(val) >= 0) {
        atomicMax(reinterpret_cast<int*>(addr), __float_as_int(val));
    } else {
        atomicMin(reinterpret_cast<unsigned int*>(addr), __float_as_uint(val));
    }
}

// ---------------------------------------------------------------------------
// edge: one wave per edge, lane d handles feature d
// ---------------------------------------------------------------------------
__global__ void gcn_edge_kernel(const float* __restrict__ inp,
                                const int* __restrict__ src,
                                const int* __restrict__ dst,
                                float* __restrict__ out, int n_edges) {
    int gtid = blockIdx.x * blockDim.x + threadIdx.x;
    int wave = gtid >> 6;
    int lane = threadIdx.x & 63;
    int nwaves = (gridDim.x * blockDim.x) >> 6;
    for (int e = wave; e < n_edges; e += nwaves) {
        int s = src[e];
        int d = dst[e];
        float v = inp[(size_t)s * D_FEAT + lane];
        atomic_max_float(out + (size_t)d * (2 * D_FEAT) + D_FEAT + lane, v);
    }
}

// ---------------------------------------------------------------------------
// finalize: where sentinel survived (in-degree 0), use own feature
// one thread = 4 floats (float4)
// ---------------------------------------------------------------------------
__global__ void gcn_finalize_kernel(const float* __restrict__ inp,
                                    float* __restrict__ out, int n_nodes) {
    int idx = blockIdx.x * blockDim.x + threadIdx.x;   // over n_nodes * 16
    int total = n_nodes * 16;
    if (idx >= total) return;
    int n = idx >> 4;
    int q = idx & 15;
    const float4* inp4 = reinterpret_cast<const float4*>(inp);
    float4* out4 = reinterpret_cast<float4*>(out);
    float4 v = out4[(size_t)n * 32 + 16 + q];
    bool any = (v.x == -INFINITY) | (v.y == -INFINITY) |
               (v.z == -INFINITY) | (v.w == -INFINITY);
    if (any) {
        float4 f = inp4[(size_t)n * 16 + q];
        if (v.x == -INFINITY) v.x = f.x;
        if (v.y == -INFINITY) v.y = f.y;
        if (v.z == -INFINITY) v.z = f.z;
        if (v.w == -INFINITY) v.w = f.w;
        out4[(size_t)n * 32 + 16 + q] = v;
    }
}

extern "C" void kernel_launch(void* const* d_in, const int* in_sizes, int n_in,
                              void* d_out, int out_size, void* d_ws, size_t ws_size,
                              hipStream_t stream) {
    const float* inp = (const float*)d_in[0];
    const int* src = (const int*)d_in[1];
    const int* dst = (const int*)d_in[2];
    float* out = (float*)d_out;

    int n_nodes = in_sizes[0] / D_FEAT;
    int n_edges = in_sizes[1];

    // init: n_nodes*16 threads
    {
        int total = n_nodes * 16;
        int block = 256;
        int grid = (total + block - 1) / block;
        gcn_init_kernel<<<grid, block, 0, stream>>>(inp, out, n_nodes);
    }
    // edge: grid-stride over edges, 1 wave/edge
    {
        int block = 256;
        int grid = 4096;   // 16384 waves, grid-stride
        gcn_edge_kernel<<<grid, block, 0, stream>>>(inp, src, dst, out, n_edges);
    }
    // finalize
    {
        int total = n_nodes * 16;
        int block = 256;
        int grid = (total + block - 1) / block;
        gcn_finalize_kernel<<<grid, block, 0, stream>>>(inp, out, n_nodes);
    }
}

// Round 2
// 466.085 us; speedup vs baseline: 1.0933x; 1.0933x over previous
//
#include <hip/hip_runtime.h>
#include <math.h>

#define D_FEAT 64
#define SCAN_BLOCK 1024

// ---------------------------------------------------------------------------
// ws layout (ints):
//   counts / cursor : n_nodes          (mutable scatter cursors)
//   offsets         : n_nodes + 1      (CSR row offsets)
//   sorted_src      : n_edges          (src node id per edge, grouped by dst)
// ---------------------------------------------------------------------------

__global__ void zero_kernel(int* __restrict__ p, int n) {
    int i = blockIdx.x * blockDim.x + threadIdx.x;
    if (i < n) p[i] = 0;
}

__global__ void hist_kernel(const int* __restrict__ dst, int* __restrict__ counts,
                            int n_edges) {
    int stride = gridDim.x * blockDim.x;
    for (int e = blockIdx.x * blockDim.x + threadIdx.x; e < n_edges; e += stride) {
        atomicAdd(&counts[dst[e]], 1);
    }
}

// single-block exclusive scan over n counts -> offsets[0..n], cursor copy
__global__ void scan_kernel(const int* __restrict__ counts,
                            int* __restrict__ offsets,
                            int* __restrict__ cursor, int n) {
    __shared__ int smem[SCAN_BLOCK];
    __shared__ int carry_s;
    int tid = threadIdx.x;
    if (tid == 0) carry_s = 0;
    __syncthreads();
    for (int base = 0; base < n; base += SCAN_BLOCK) {
        int i = base + tid;
        int v = (i < n) ? counts[i] : 0;
        smem[tid] = v;
        __syncthreads();
        // Hillis-Steele inclusive scan
        for (int off = 1; off < SCAN_BLOCK; off <<= 1) {
            int t = (tid >= off) ? smem[tid - off] : 0;
            __syncthreads();
            smem[tid] += t;
            __syncthreads();
        }
        int incl = smem[tid];
        int carry = carry_s;
        __syncthreads();                       // all reads of carry_s done
        if (tid == SCAN_BLOCK - 1) carry_s = carry + incl;
        int excl = carry + incl - v;
        if (i < n) { offsets[i] = excl; cursor[i] = excl; }
        __syncthreads();                       // carry_s visible next iter
    }
    if (tid == 0) offsets[n] = carry_s;
}

__global__ void scatter_kernel(const int* __restrict__ src,
                               const int* __restrict__ dst,
                               int* __restrict__ cursor,
                               int* __restrict__ sorted_src, int n_edges) {
    int stride = gridDim.x * blockDim.x;
    for (int e = blockIdx.x * blockDim.x + threadIdx.x; e < n_edges; e += stride) {
        int pos = atomicAdd(&cursor[dst[e]], 1);
        sorted_src[pos] = src[e];
    }
}

// one wave per node; lane = feature. out[n][0:64]=inputs[n],
// out[n][64:128]=max over incoming msgs (or inputs[n] if none).
__global__ void pull_max_kernel(const float* __restrict__ inp,
                                const int* __restrict__ offsets,
                                const int* __restrict__ sorted_src,
                                float* __restrict__ out, int n_nodes) {
    int gtid = blockIdx.x * blockDim.x + threadIdx.x;
    int node = gtid >> 6;
    int lane = threadIdx.x & 63;
    if (node >= n_nodes) return;

    int beg = offsets[node];
    int end = offsets[node + 1];

    float own = inp[(size_t)node * D_FEAT + lane];
    float m = -INFINITY;

    int j = beg;
    for (; j + 3 < end; j += 4) {
        int s0 = sorted_src[j];
        int s1 = sorted_src[j + 1];
        int s2 = sorted_src[j + 2];
        int s3 = sorted_src[j + 3];
        float v0 = inp[(size_t)s0 * D_FEAT + lane];
        float v1 = inp[(size_t)s1 * D_FEAT + lane];
        float v2 = inp[(size_t)s2 * D_FEAT + lane];
        float v3 = inp[(size_t)s3 * D_FEAT + lane];
        m = fmaxf(m, fmaxf(fmaxf(v0, v1), fmaxf(v2, v3)));
    }
    for (; j < end; ++j) {
        m = fmaxf(m, inp[(size_t)sorted_src[j] * D_FEAT + lane]);
    }
    if (end == beg) m = own;

    out[(size_t)node * (2 * D_FEAT) + lane] = own;
    out[(size_t)node * (2 * D_FEAT) + D_FEAT + lane] = m;
}

extern "C" void kernel_launch(void* const* d_in, const int* in_sizes, int n_in,
                              void* d_out, int out_size, void* d_ws, size_t ws_size,
                              hipStream_t stream) {
    const float* inp = (const float*)d_in[0];
    const int* src = (const int*)d_in[1];
    const int* dst = (const int*)d_in[2];
    float* out = (float*)d_out;

    int n_nodes = in_sizes[0] / D_FEAT;
    int n_edges = in_sizes[1];

    int* ws = (int*)d_ws;
    int* counts_cursor = ws;                       // n_nodes
    int* offsets = ws + n_nodes;                   // n_nodes + 1
    int* sorted_src = ws + 2 * n_nodes + 1;        // n_edges

    // 1. zero counters
    {
        int block = 256;
        int grid = (n_nodes + block - 1) / block;
        zero_kernel<<<grid, block, 0, stream>>>(counts_cursor, n_nodes);
    }
    // 2. histogram of dst
    {
        hist_kernel<<<2048, 256, 0, stream>>>(dst, counts_cursor, n_edges);
    }
    // 3. exclusive scan -> offsets, and re-init cursors
    {
        scan_kernel<<<1, SCAN_BLOCK, 0, stream>>>(counts_cursor, offsets,
                                                  counts_cursor, n_nodes);
    }
    // 4. scatter src ids grouped by dst
    {
        scatter_kernel<<<2048, 256, 0, stream>>>(src, dst, counts_cursor,
                                                 sorted_src, n_edges);
    }
    // 5. pull-style segment max + concat
    {
        int total = n_nodes * 64;
        int block = 256;
        int grid = (total + block - 1) / block;
        pull_max_kernel<<<grid, block, 0, stream>>>(inp, offsets, sorted_src,
                                                    out, n_nodes);
    }
}

// Round 3
// 300.529 us; speedup vs baseline: 1.6955x; 1.5509x over previous
//
#include <hip/hip_runtime.h>
#include <math.h>

#define D_FEAT 64
#define SCAN_BLOCK 1024

// ---------------------------------------------------------------------------
// ws layout (ints):
//   counts / cursor : n_nodes
//   offsets         : n_nodes + 1
//   blocksums       : numScanBlocks (+ pad)
//   sorted_src      : n_edges
// ---------------------------------------------------------------------------

__global__ void zero_kernel(int* __restrict__ p, int n) {
    int i = blockIdx.x * blockDim.x + threadIdx.x;
    if (i < n) p[i] = 0;
}

__global__ void hist_kernel(const int* __restrict__ dst, int* __restrict__ counts,
                            int n_edges) {
    int stride = gridDim.x * blockDim.x;
    for (int e = blockIdx.x * blockDim.x + threadIdx.x; e < n_edges; e += stride) {
        atomicAdd(&counts[dst[e]], 1);
    }
}

// Phase A: per-block scan of 1024-element tiles; local-exclusive into offsets,
// tile total into blocksums[b].
__global__ void scanA_kernel(const int* __restrict__ counts,
                             int* __restrict__ offsets,
                             int* __restrict__ blocksums, int n) {
    __shared__ int smem[SCAN_BLOCK];
    int tid = threadIdx.x;
    int i = blockIdx.x * SCAN_BLOCK + tid;
    int v = (i < n) ? counts[i] : 0;
    smem[tid] = v;
    __syncthreads();
    for (int off = 1; off < SCAN_BLOCK; off <<= 1) {
        int t = (tid >= off) ? smem[tid - off] : 0;
        __syncthreads();
        smem[tid] += t;
        __syncthreads();
    }
    if (i < n) offsets[i] = smem[tid] - v;
    if (tid == SCAN_BLOCK - 1) blocksums[blockIdx.x] = smem[tid];
}

// Phase B: single block exclusive-scans the (<=1024) block sums in place.
__global__ void scanB_kernel(int* __restrict__ blocksums, int nb) {
    __shared__ int smem[SCAN_BLOCK];
    int tid = threadIdx.x;
    int v = (tid < nb) ? blocksums[tid] : 0;
    smem[tid] = v;
    __syncthreads();
    for (int off = 1; off < SCAN_BLOCK; off <<= 1) {
        int t = (tid >= off) ? smem[tid - off] : 0;
        __syncthreads();
        smem[tid] += t;
        __syncthreads();
    }
    if (tid < nb) blocksums[tid] = smem[tid] - v;
}

// Phase C: add block offsets, copy to cursor, set offsets[n] = n_edges.
__global__ void scanC_kernel(int* __restrict__ offsets, int* __restrict__ cursor,
                             const int* __restrict__ blocksums, int n, int n_edges) {
    int i = blockIdx.x * SCAN_BLOCK + threadIdx.x;
    if (i < n) {
        int o = offsets[i] + blocksums[blockIdx.x];
        offsets[i] = o;
        cursor[i] = o;
    }
    if (i == 0) offsets[n] = n_edges;
}

__global__ void scatter_kernel(const int* __restrict__ src,
                               const int* __restrict__ dst,
                               int* __restrict__ cursor,
                               int* __restrict__ sorted_src, int n_edges) {
    int stride = gridDim.x * blockDim.x;
    for (int e = blockIdx.x * blockDim.x + threadIdx.x; e < n_edges; e += stride) {
        int pos = atomicAdd(&cursor[dst[e]], 1);
        sorted_src[pos] = src[e];
    }
}

// one wave per node. 4 groups x 16 lanes; group g handles edges beg+g, beg+g+4,...
// with float4 gathers (16 lanes x 16B = one 256B transaction per edge).
__global__ void pull_max_kernel(const float* __restrict__ inp,
                                const int* __restrict__ offsets,
                                const int* __restrict__ sorted_src,
                                float* __restrict__ out, int n_nodes) {
    int gtid = blockIdx.x * blockDim.x + threadIdx.x;
    int node = gtid >> 6;
    if (node >= n_nodes) return;
    int lane = threadIdx.x & 63;
    int g = lane >> 4;
    int l = lane & 15;

    int beg = offsets[node];
    int end = offsets[node + 1];

    const float4* inp4 = reinterpret_cast<const float4*>(inp);
    float4 own = inp4[(size_t)node * 16 + l];

    float4 m;
    m.x = -INFINITY; m.y = -INFINITY; m.z = -INFINITY; m.w = -INFINITY;
    for (int j = beg + g; j < end; j += 4) {
        int s = sorted_src[j];
        float4 v = inp4[(size_t)s * 16 + l];
        m.x = fmaxf(m.x, v.x);
        m.y = fmaxf(m.y, v.y);
        m.z = fmaxf(m.z, v.z);
        m.w = fmaxf(m.w, v.w);
    }
    // reduce across the 4 groups (same l, g ^ {1,2})
    m.x = fmaxf(m.x, __shfl_xor(m.x, 16, 64));
    m.y = fmaxf(m.y, __shfl_xor(m.y, 16, 64));
    m.z = fmaxf(m.z, __shfl_xor(m.z, 16, 64));
    m.w = fmaxf(m.w, __shfl_xor(m.w, 16, 64));
    m.x = fmaxf(m.x, __shfl_xor(m.x, 32, 64));
    m.y = fmaxf(m.y, __shfl_xor(m.y, 32, 64));
    m.z = fmaxf(m.z, __shfl_xor(m.z, 32, 64));
    m.w = fmaxf(m.w, __shfl_xor(m.w, 32, 64));

    if (beg == end) m = own;   // isolated node keeps own feature

    float4* out4 = reinterpret_cast<float4*>(out);
    if (lane < 16) {
        out4[(size_t)node * 32 + l] = own;          // first half: inputs
    } else if (lane < 32) {
        out4[(size_t)node * 32 + 16 + l] = m;       // second half: max agg
    }
}

extern "C" void kernel_launch(void* const* d_in, const int* in_sizes, int n_in,
                              void* d_out, int out_size, void* d_ws, size_t ws_size,
                              hipStream_t stream) {
    const float* inp = (const float*)d_in[0];
    const int* src = (const int*)d_in[1];
    const int* dst = (const int*)d_in[2];
    float* out = (float*)d_out;

    int n_nodes = in_sizes[0] / D_FEAT;
    int n_edges = in_sizes[1];

    int nScanBlocks = (n_nodes + SCAN_BLOCK - 1) / SCAN_BLOCK;

    int* ws = (int*)d_ws;
    int* counts_cursor = ws;                               // n_nodes
    int* offsets = ws + n_nodes;                           // n_nodes + 1
    int* blocksums = ws + 2 * n_nodes + 1;                 // nScanBlocks
    int* sorted_src = ws + 2 * n_nodes + 1 + nScanBlocks;  // n_edges

    // 1. zero counters
    {
        int block = 256;
        int grid = (n_nodes + block - 1) / block;
        zero_kernel<<<grid, block, 0, stream>>>(counts_cursor, n_nodes);
    }
    // 2. histogram of dst
    hist_kernel<<<2048, 256, 0, stream>>>(dst, counts_cursor, n_edges);
    // 3. three-phase exclusive scan -> offsets + cursor
    scanA_kernel<<<nScanBlocks, SCAN_BLOCK, 0, stream>>>(counts_cursor, offsets,
                                                         blocksums, n_nodes);
    scanB_kernel<<<1, SCAN_BLOCK, 0, stream>>>(blocksums, nScanBlocks);
    scanC_kernel<<<nScanBlocks, SCAN_BLOCK, 0, stream>>>(offsets, counts_cursor,
                                                         blocksums, n_nodes, n_edges);
    // 4. scatter src ids grouped by dst
    scatter_kernel<<<2048, 256, 0, stream>>>(src, dst, counts_cursor,
                                             sorted_src, n_edges);
    // 5. pull-style segment max + concat
    {
        int total = n_nodes * 64;
        int block = 256;
        int grid = (total + block - 1) / block;
        pull_max_kernel<<<grid, block, 0, stream>>>(inp, offsets, sorted_src,
                                                    out, n_nodes);
    }
}

// Round 4
// 256.699 us; speedup vs baseline: 1.9850x; 1.1707x over previous
//
#include <hip/hip_runtime.h>
#include <math.h>

#define D_FEAT 64
#define SCAN_BLOCK 1024
#define N_RANGES 8          // one dst-range per XCD (blockIdx % 8 -> XCD)

// ---------------------------------------------------------------------------
// ws layout (ints):
//   counts / cursor : n_nodes
//   offsets         : n_nodes + 1
//   blocksums       : nScanBlocks
//   sorted_src      : n_edges
// ---------------------------------------------------------------------------

__global__ void zero_kernel(int* __restrict__ p, int n) {
    int i = blockIdx.x * blockDim.x + threadIdx.x;
    if (i < n) p[i] = 0;
}

// XCD-partitioned histogram: block (r, c) streams chunk c of dst, counts only
// dst in range r. counts-lines for a range stay in one XCD's L2.
__global__ void hist_part_kernel(const int* __restrict__ dst,
                                 int* __restrict__ counts,
                                 int n_edges, int nodes_per_range) {
    int r = blockIdx.x & (N_RANGES - 1);
    int c = blockIdx.x / N_RANGES;
    int nchunks = gridDim.x / N_RANGES;
    int lo = r * nodes_per_range;
    int hi = lo + nodes_per_range;
    int stride = nchunks * blockDim.x;
    for (int e = c * blockDim.x + threadIdx.x; e < n_edges; e += stride) {
        int d = dst[e];
        if (d >= lo && d < hi) atomicAdd(&counts[d], 1);
    }
}

// Phase A: per-block scan of 1024-element tiles
__global__ void scanA_kernel(const int* __restrict__ counts,
                             int* __restrict__ offsets,
                             int* __restrict__ blocksums, int n) {
    __shared__ int smem[SCAN_BLOCK];
    int tid = threadIdx.x;
    int i = blockIdx.x * SCAN_BLOCK + tid;
    int v = (i < n) ? counts[i] : 0;
    smem[tid] = v;
    __syncthreads();
    for (int off = 1; off < SCAN_BLOCK; off <<= 1) {
        int t = (tid >= off) ? smem[tid - off] : 0;
        __syncthreads();
        smem[tid] += t;
        __syncthreads();
    }
    if (i < n) offsets[i] = smem[tid] - v;
    if (tid == SCAN_BLOCK - 1) blocksums[blockIdx.x] = smem[tid];
}

// Phase B: single block exclusive-scans the (<=1024) block sums in place.
__global__ void scanB_kernel(int* __restrict__ blocksums, int nb) {
    __shared__ int smem[SCAN_BLOCK];
    int tid = threadIdx.x;
    int v = (tid < nb) ? blocksums[tid] : 0;
    smem[tid] = v;
    __syncthreads();
    for (int off = 1; off < SCAN_BLOCK; off <<= 1) {
        int t = (tid >= off) ? smem[tid - off] : 0;
        __syncthreads();
        smem[tid] += t;
        __syncthreads();
    }
    if (tid < nb) blocksums[tid] = smem[tid] - v;
}

// Phase C: add block offsets, copy to cursor, set offsets[n] = n_edges.
__global__ void scanC_kernel(int* __restrict__ offsets, int* __restrict__ cursor,
                             const int* __restrict__ blocksums, int n, int n_edges) {
    int i = blockIdx.x * SCAN_BLOCK + threadIdx.x;
    if (i < n) {
        int o = offsets[i] + blocksums[blockIdx.x];
        offsets[i] = o;
        cursor[i] = o;
    }
    if (i == 0) offsets[n] = n_edges;
}

// XCD-partitioned scatter: block (r, c) streams chunk c of (src,dst), scatters
// only edges with dst in range r. cursor + sorted_src region for a range are
// L2-local to one XCD -> atomics don't ping-pong, writes combine into lines.
__global__ void scatter_part_kernel(const int* __restrict__ src,
                                    const int* __restrict__ dst,
                                    int* __restrict__ cursor,
                                    int* __restrict__ sorted_src,
                                    int n_edges, int nodes_per_range) {
    int r = blockIdx.x & (N_RANGES - 1);
    int c = blockIdx.x / N_RANGES;
    int nchunks = gridDim.x / N_RANGES;
    int lo = r * nodes_per_range;
    int hi = lo + nodes_per_range;
    int stride = nchunks * blockDim.x;
    for (int e = c * blockDim.x + threadIdx.x; e < n_edges; e += stride) {
        int d = dst[e];
        if (d >= lo && d < hi) {
            int pos = atomicAdd(&cursor[d], 1);
            sorted_src[pos] = src[e];
        }
    }
}

// one wave per node. 4 groups x 16 lanes; group g handles edges beg+g, beg+g+4,...
// with float4 gathers (16 lanes x 16B = one 256B transaction per edge).
__global__ void pull_max_kernel(const float* __restrict__ inp,
                                const int* __restrict__ offsets,
                                const int* __restrict__ sorted_src,
                                float* __restrict__ out, int n_nodes) {
    int gtid = blockIdx.x * blockDim.x + threadIdx.x;
    int node = gtid >> 6;
    if (node >= n_nodes) return;
    int lane = threadIdx.x & 63;
    int g = lane >> 4;
    int l = lane & 15;

    int beg = offsets[node];
    int end = offsets[node + 1];

    const float4* inp4 = reinterpret_cast<const float4*>(inp);
    float4 own = inp4[(size_t)node * 16 + l];

    float4 m;
    m.x = -INFINITY; m.y = -INFINITY; m.z = -INFINITY; m.w = -INFINITY;
    for (int j = beg + g; j < end; j += 4) {
        int s = sorted_src[j];
        float4 v = inp4[(size_t)s * 16 + l];
        m.x = fmaxf(m.x, v.x);
        m.y = fmaxf(m.y, v.y);
        m.z = fmaxf(m.z, v.z);
        m.w = fmaxf(m.w, v.w);
    }
    m.x = fmaxf(m.x, __shfl_xor(m.x, 16, 64));
    m.y = fmaxf(m.y, __shfl_xor(m.y, 16, 64));
    m.z = fmaxf(m.z, __shfl_xor(m.z, 16, 64));
    m.w = fmaxf(m.w, __shfl_xor(m.w, 16, 64));
    m.x = fmaxf(m.x, __shfl_xor(m.x, 32, 64));
    m.y = fmaxf(m.y, __shfl_xor(m.y, 32, 64));
    m.z = fmaxf(m.z, __shfl_xor(m.z, 32, 64));
    m.w = fmaxf(m.w, __shfl_xor(m.w, 32, 64));

    if (beg == end) m = own;   // isolated node keeps own feature

    float4* out4 = reinterpret_cast<float4*>(out);
    if (lane < 16) {
        out4[(size_t)node * 32 + l] = own;          // first half: inputs
    } else if (lane < 32) {
        out4[(size_t)node * 32 + 16 + l] = m;       // second half: max agg
    }
}

extern "C" void kernel_launch(void* const* d_in, const int* in_sizes, int n_in,
                              void* d_out, int out_size, void* d_ws, size_t ws_size,
                              hipStream_t stream) {
    const float* inp = (const float*)d_in[0];
    const int* src = (const int*)d_in[1];
    const int* dst = (const int*)d_in[2];
    float* out = (float*)d_out;

    int n_nodes = in_sizes[0] / D_FEAT;
    int n_edges = in_sizes[1];

    int nScanBlocks = (n_nodes + SCAN_BLOCK - 1) / SCAN_BLOCK;
    int nodes_per_range = (n_nodes + N_RANGES - 1) / N_RANGES;

    int* ws = (int*)d_ws;
    int* counts_cursor = ws;                               // n_nodes
    int* offsets = ws + n_nodes;                           // n_nodes + 1
    int* blocksums = ws + 2 * n_nodes + 1;                 // nScanBlocks
    int* sorted_src = ws + 2 * n_nodes + 1 + nScanBlocks;  // n_edges

    // 1. zero counters
    {
        int block = 256;
        int grid = (n_nodes + block - 1) / block;
        zero_kernel<<<grid, block, 0, stream>>>(counts_cursor, n_nodes);
    }
    // 2. XCD-partitioned histogram of dst  (8 ranges x 160 chunks)
    hist_part_kernel<<<N_RANGES * 160, 256, 0, stream>>>(dst, counts_cursor,
                                                         n_edges, nodes_per_range);
    // 3. three-phase exclusive scan -> offsets + cursor
    scanA_kernel<<<nScanBlocks, SCAN_BLOCK, 0, stream>>>(counts_cursor, offsets,
                                                         blocksums, n_nodes);
    scanB_kernel<<<1, SCAN_BLOCK, 0, stream>>>(blocksums, nScanBlocks);
    scanC_kernel<<<nScanBlocks, SCAN_BLOCK, 0, stream>>>(offsets, counts_cursor,
                                                         blocksums, n_nodes, n_edges);
    // 4. XCD-partitioned scatter of src ids grouped by dst
    scatter_part_kernel<<<N_RANGES * 160, 256, 0, stream>>>(src, dst, counts_cursor,
                                                            sorted_src, n_edges,
                                                            nodes_per_range);
    // 5. pull-style segment max + concat
    {
        int total = n_nodes * 64;
        int block = 256;
        int grid = (total + block - 1) / block;
        pull_max_kernel<<<grid, block, 0, stream>>>(inp, offsets, sorted_src,
                                                    out, n_nodes);
    }
}

// Round 6
// 244.668 us; speedup vs baseline: 2.0826x; 1.0492x over previous
//
#include <hip/hip_runtime.h>
#include <math.h>

#define D_FEAT 64
#define SCAN_BLOCK 1024
#define NG 8          // edge groups (private counters, one per XCD)
#define NR 8          // dst ranges (XCD-local scatter writes)

// ---------------------------------------------------------------------------
// main ws layout (ints):
//   priv       : NG * n_nodes     (per-group counts -> cross-group prefixes/cursors)
//   offsets    : n_nodes + 1
//   blocksums  : nScanBlocks
//   sorted_src : n_edges
// fallback layout (round-4): counts n | offsets n+1 | blocksums | sorted E
// ---------------------------------------------------------------------------

__global__ void zero_kernel(int* __restrict__ p, int n) {
    int i = blockIdx.x * blockDim.x + threadIdx.x;
    if (i < n) p[i] = 0;
}

// wave-shuffle block exclusive scan; requires blockDim.x == 1024
__device__ __forceinline__ int block_scan_excl_1024(int v, int* smem16) {
    int lane = threadIdx.x & 63;
    int wid  = threadIdx.x >> 6;
    int x = v;
    #pragma unroll
    for (int d = 1; d < 64; d <<= 1) {
        int t = __shfl_up(x, d, 64);
        if (lane >= d) x += t;
    }
    if (lane == 63) smem16[wid] = x;          // wave inclusive totals
    __syncthreads();
    if (wid == 0) {
        int s = (lane < 16) ? smem16[lane] : 0;
        #pragma unroll
        for (int d = 1; d < 16; d <<= 1) {
            int t = __shfl_up(s, d, 64);
            if (lane >= d) s += t;
        }
        if (lane < 16) smem16[lane] = s;      // inclusive scan of wave totals
    }
    __syncthreads();
    int base = (wid > 0) ? smem16[wid - 1] : 0;
    return base + x - v;                      // exclusive prefix
}

// =========================== main path =====================================

// edge-group-partitioned count: group g (blockIdx&7 -> XCD g) streams its
// contiguous 1/8 of the edge list once, coalesced; atomics hit priv[g][*],
// which only XCD g touches -> L2-local.
__global__ void count_group_kernel(const int* __restrict__ dst,
                                   int* __restrict__ priv,
                                   int n_nodes, int n_edges, int egroup) {
    int g = blockIdx.x & (NG - 1);
    int c = blockIdx.x >> 3;
    int nchunks = gridDim.x >> 3;
    int ebeg = g * egroup;
    int eend = ebeg + egroup; if (eend > n_edges) eend = n_edges;
    int* cnt = priv + (size_t)g * n_nodes;
    int stride = nchunks * blockDim.x;
    for (int e = ebeg + c * blockDim.x + threadIdx.x; e < eend; e += stride) {
        atomicAdd(&cnt[dst[e]], 1);
    }
}

// fused: per-node cross-group exclusive prefix (rewrites priv in place),
// node totals block-scanned into offsets + blocksums.
__global__ void scanA_fused_kernel(int* __restrict__ priv,
                                   int* __restrict__ offsets,
                                   int* __restrict__ blocksums, int n_nodes) {
    __shared__ int smem16[16];
    int i = blockIdx.x * SCAN_BLOCK + threadIdx.x;
    int total = 0;
    if (i < n_nodes) {
        int run = 0;
        #pragma unroll
        for (int g = 0; g < NG; ++g) {
            size_t idx = (size_t)g * n_nodes + i;
            int t = priv[idx];
            priv[idx] = run;      // becomes sub-segment start (relative)
            run += t;
        }
        total = run;
    }
    int excl = block_scan_excl_1024(total, smem16);
    if (i < n_nodes) offsets[i] = excl;
    if (threadIdx.x == SCAN_BLOCK - 1) blocksums[blockIdx.x] = excl + total;
}

__global__ void scanB_kernel(int* __restrict__ blocksums, int nb) {
    __shared__ int smem16[16];
    int v = ((int)threadIdx.x < nb) ? blocksums[threadIdx.x] : 0;
    int e = block_scan_excl_1024(v, smem16);
    if ((int)threadIdx.x < nb) blocksums[threadIdx.x] = e;
}

__global__ void scanC_kernel(int* __restrict__ offsets,
                             const int* __restrict__ blocksums,
                             int n, int n_edges) {
    int i = blockIdx.x * SCAN_BLOCK + threadIdx.x;
    if (i < n) offsets[i] += blocksums[blockIdx.x];
    if (i == 0) offsets[n] = n_edges;
}

// scatter: block (r,g,c). r = blockIdx&7 -> XCD r. Processes group g's edge
// chunk, keeps only dst in range r. Cursor atomics (priv slice for range r)
// and sorted_src writes (range-r segment) are both XCD-r L2-local.
__global__ void scatter_rg_kernel(const int* __restrict__ src,
                                  const int* __restrict__ dst,
                                  const int* __restrict__ offsets,
                                  int* __restrict__ priv,
                                  int* __restrict__ sorted_src,
                                  int n_nodes, int n_edges, int egroup,
                                  int nodes_per_range) {
    int r = blockIdx.x & (NR - 1);
    int g = (blockIdx.x >> 3) & (NG - 1);
    int c = blockIdx.x >> 6;
    int nchunks = gridDim.x >> 6;
    int lo = r * nodes_per_range;
    int hi = lo + nodes_per_range;
    int ebeg = g * egroup;
    int eend = ebeg + egroup; if (eend > n_edges) eend = n_edges;
    int* cur = priv + (size_t)g * n_nodes;
    int stride = nchunks * blockDim.x;
    for (int e = ebeg + c * blockDim.x + threadIdx.x; e < eend; e += stride) {
        int d = dst[e];
        if (d >= lo && d < hi) {
            int pos = offsets[d] + atomicAdd(&cur[d], 1);
            sorted_src[pos] = src[e];
        }
    }
}

// ========================= fallback path (round-4) =========================

__global__ void hist_part_kernel(const int* __restrict__ dst,
                                 int* __restrict__ counts,
                                 int n_edges, int nodes_per_range) {
    int r = blockIdx.x & (NR - 1);
    int c = blockIdx.x / NR;
    int nchunks = gridDim.x / NR;
    int lo = r * nodes_per_range;
    int hi = lo + nodes_per_range;
    int stride = nchunks * blockDim.x;
    for (int e = c * blockDim.x + threadIdx.x; e < n_edges; e += stride) {
        int d = dst[e];
        if (d >= lo && d < hi) atomicAdd(&counts[d], 1);
    }
}

__global__ void scanA_plain_kernel(const int* __restrict__ counts,
                                   int* __restrict__ offsets,
                                   int* __restrict__ blocksums, int n) {
    __shared__ int smem16[16];
    int i = blockIdx.x * SCAN_BLOCK + threadIdx.x;
    int v = (i < n) ? counts[i] : 0;
    int e = block_scan_excl_1024(v, smem16);
    if (i < n) offsets[i] = e;
    if (threadIdx.x == SCAN_BLOCK - 1) blocksums[blockIdx.x] = e + v;
}

__global__ void scanC_plain_kernel(int* __restrict__ offsets,
                                   int* __restrict__ cursor,
                                   const int* __restrict__ blocksums,
                                   int n, int n_edges) {
    int i = blockIdx.x * SCAN_BLOCK + threadIdx.x;
    if (i < n) {
        int o = offsets[i] + blocksums[blockIdx.x];
        offsets[i] = o;
        cursor[i] = o;
    }
    if (i == 0) offsets[n] = n_edges;
}

__global__ void scatter_part_kernel(const int* __restrict__ src,
                                    const int* __restrict__ dst,
                                    int* __restrict__ cursor,
                                    int* __restrict__ sorted_src,
                                    int n_edges, int nodes_per_range) {
    int r = blockIdx.x & (NR - 1);
    int c = blockIdx.x / NR;
    int nchunks = gridDim.x / NR;
    int lo = r * nodes_per_range;
    int hi = lo + nodes_per_range;
    int stride = nchunks * blockDim.x;
    for (int e = c * blockDim.x + threadIdx.x; e < n_edges; e += stride) {
        int d = dst[e];
        if (d >= lo && d < hi) {
            int pos = atomicAdd(&cursor[d], 1);
            sorted_src[pos] = src[e];
        }
    }
}

// ============================== pull phase =================================

// one wave per node; 4 groups x 16 lanes, float4 gathers, 2-deep unroll.
__global__ void pull_max_kernel(const float* __restrict__ inp,
                                const int* __restrict__ offsets,
                                const int* __restrict__ sorted_src,
                                float* __restrict__ out, int n_nodes) {
    int gtid = blockIdx.x * blockDim.x + threadIdx.x;
    int node = gtid >> 6;
    if (node >= n_nodes) return;
    int lane = threadIdx.x & 63;
    int g = lane >> 4;
    int l = lane & 15;

    int beg = offsets[node];
    int end = offsets[node + 1];

    const float4* inp4 = reinterpret_cast<const float4*>(inp);
    float4 own = inp4[(size_t)node * 16 + l];

    float4 m;
    m.x = -INFINITY; m.y = -INFINITY; m.z = -INFINITY; m.w = -INFINITY;
    int j = beg + g;
    for (; j + 4 < end; j += 8) {
        int s0 = sorted_src[j];
        int s1 = sorted_src[j + 4];
        float4 v0 = inp4[(size_t)s0 * 16 + l];
        float4 v1 = inp4[(size_t)s1 * 16 + l];
        m.x = fmaxf(m.x, fmaxf(v0.x, v1.x));
        m.y = fmaxf(m.y, fmaxf(v0.y, v1.y));
        m.z = fmaxf(m.z, fmaxf(v0.z, v1.z));
        m.w = fmaxf(m.w, fmaxf(v0.w, v1.w));
    }
    if (j < end) {
        int s = sorted_src[j];
        float4 v = inp4[(size_t)s * 16 + l];
        m.x = fmaxf(m.x, v.x);
        m.y = fmaxf(m.y, v.y);
        m.z = fmaxf(m.z, v.z);
        m.w = fmaxf(m.w, v.w);
    }
    m.x = fmaxf(m.x, __shfl_xor(m.x, 16, 64));
    m.y = fmaxf(m.y, __shfl_xor(m.y, 16, 64));
    m.z = fmaxf(m.z, __shfl_xor(m.z, 16, 64));
    m.w = fmaxf(m.w, __shfl_xor(m.w, 16, 64));
    m.x = fmaxf(m.x, __shfl_xor(m.x, 32, 64));
    m.y = fmaxf(m.y, __shfl_xor(m.y, 32, 64));
    m.z = fmaxf(m.z, __shfl_xor(m.z, 32, 64));
    m.w = fmaxf(m.w, __shfl_xor(m.w, 32, 64));

    if (beg == end) m = own;   // isolated node keeps own feature

    float4* out4 = reinterpret_cast<float4*>(out);
    if (lane < 16) {
        out4[(size_t)node * 32 + l] = own;
    } else if (lane < 32) {
        out4[(size_t)node * 32 + 16 + l] = m;
    }
}

// ===========================================================================

extern "C" void kernel_launch(void* const* d_in, const int* in_sizes, int n_in,
                              void* d_out, int out_size, void* d_ws, size_t ws_size,
                              hipStream_t stream) {
    const float* inp = (const float*)d_in[0];
    const int* src = (const int*)d_in[1];
    const int* dst = (const int*)d_in[2];
    float* out = (float*)d_out;

    int n_nodes = in_sizes[0] / D_FEAT;
    int n_edges = in_sizes[1];

    int nScanBlocks = (n_nodes + SCAN_BLOCK - 1) / SCAN_BLOCK;
    int nodes_per_range = (n_nodes + NR - 1) / NR;
    int egroup = (n_edges + NG - 1) / NG;

    int* ws = (int*)d_ws;
    size_t need_main = ((size_t)NG * n_nodes + (size_t)(n_nodes + 1) +
                        (size_t)nScanBlocks + (size_t)n_edges) * sizeof(int);

    if (ws_size >= need_main) {
        // ------------------- main path -------------------
        int* priv = ws;                                        // NG*n
        int* offsets = ws + (size_t)NG * n_nodes;              // n+1
        int* blocksums = offsets + n_nodes + 1;                // nScanBlocks
        int* sorted_src = blocksums + nScanBlocks;             // E

        {
            int total = NG * n_nodes;
            zero_kernel<<<(total + 255) / 256, 256, 0, stream>>>(priv, total);
        }
        count_group_kernel<<<NG * 64, 256, 0, stream>>>(dst, priv, n_nodes,
                                                        n_edges, egroup);
        scanA_fused_kernel<<<nScanBlocks, SCAN_BLOCK, 0, stream>>>(priv, offsets,
                                                                   blocksums, n_nodes);
        scanB_kernel<<<1, SCAN_BLOCK, 0, stream>>>(blocksums, nScanBlocks);
        scanC_kernel<<<nScanBlocks, SCAN_BLOCK, 0, stream>>>(offsets, blocksums,
                                                             n_nodes, n_edges);
        scatter_rg_kernel<<<NR * NG * 20, 256, 0, stream>>>(src, dst, offsets,
                                                            priv, sorted_src,
                                                            n_nodes, n_edges,
                                                            egroup, nodes_per_range);
        {
            int total = n_nodes * 64;
            pull_max_kernel<<<(total + 255) / 256, 256, 0, stream>>>(
                inp, offsets, sorted_src, out, n_nodes);
        }
    } else {
        // ------------------- fallback (round-4 layout) -------------------
        int* counts_cursor = ws;                               // n
        int* offsets = ws + n_nodes;                           // n+1
        int* blocksums = offsets + n_nodes + 1;                // nScanBlocks
        int* sorted_src = blocksums + nScanBlocks;             // E

        zero_kernel<<<(n_nodes + 255) / 256, 256, 0, stream>>>(counts_cursor, n_nodes);
        hist_part_kernel<<<NR * 160, 256, 0, stream>>>(dst, counts_cursor,
                                                       n_edges, nodes_per_range);
        scanA_plain_kernel<<<nScanBlocks, SCAN_BLOCK, 0, stream>>>(counts_cursor,
                                                                   offsets, blocksums,
                                                                   n_nodes);
        scanB_kernel<<<1, SCAN_BLOCK, 0, stream>>>(blocksums, nScanBlocks);
        scanC_plain_kernel<<<nScanBlocks, SCAN_BLOCK, 0, stream>>>(offsets,
                                                                   counts_cursor,
                                                                   blocksums,
                                                                   n_nodes, n_edges);
        scatter_part_kernel<<<NR * 160, 256, 0, stream>>>(src, dst, counts_cursor,
                                                          sorted_src, n_edges,
                                                          nodes_per_range);
        {
            int total = n_nodes * 64;
            pull_max_kernel<<<(total + 255) / 256, 256, 0, stream>>>(
                inp, offsets, sorted_src, out, n_nodes);
        }
    }
}